// Round 5
// baseline (578.365 us; speedup 1.0000x reference)
//
#include <hip/hip_runtime.h>

#define NSEQ   4096
#define TSTEPS 512
#define FIN    5
#define HID    64
#define SPB    16     // sequences per block (MFMA M)
#define BLK    256    // 4 waves, 1/SIMD — dual-chain stagger within each wave

// Neutral names — do NOT reuse HIP vector-type names like short8 (R4 crash)
typedef __attribute__((ext_vector_type(8))) short bsh8;    // 8 bf16 in 4 VGPRs
typedef __attribute__((ext_vector_type(4))) float f32x4;   // MFMA accumulator
typedef __attribute__((ext_vector_type(4))) int   i32x4;

#define MFMA16(A, B, C) __builtin_amdgcn_mfma_f32_16x16x32_bf16((A), (B), (C), 0, 0, 0)

// Gate pre-scaling folded into weights/biases so MFMA output is exp2-ready.
//   i,f,o rows scaled by -log2e  -> sigmoid = rcp(1 + exp2(m))
//   g rows scaled by +2*log2e    -> tanh    = (Eg-1)/(Eg+1)
//   c tracked as cs = 2*log2e*c  -> tanh(c) = (Ec-1)/(Ec+1)
#define LOG2E 1.4426950408889634f
#define SNEG  (-LOG2E)
#define SPOS  (2.0f * LOG2E)

struct Frag2 { bsh8 hi; bsh8 lo; };

__device__ __forceinline__ unsigned short bf16hi_rn(float x) {
    unsigned u = __float_as_uint(x);
    return (unsigned short)((u + 0x7fffu + ((u >> 16) & 1u)) >> 16);
}
__device__ __forceinline__ void split_bf16(float v, unsigned short& h, unsigned short& l) {
    h = bf16hi_rn(v);
    float hf_ = __uint_as_float(((unsigned)h) << 16);
    l = bf16hi_rn(v - hf_);
}

__device__ __forceinline__ Frag2 load_whh_frag(const float* __restrict__ Whh, int row, int k, float scale) {
    const float* p = Whh + row * HID + k;
    Frag2 r;
#pragma unroll
    for (int j = 0; j < 8; ++j) {
        unsigned short h, l;
        split_bf16(scale * p[j], h, l);
        r.hi[j] = (short)h; r.lo[j] = (short)l;
    }
    return r;
}
__device__ __forceinline__ Frag2 load_wih_frag(const float* __restrict__ Wih,
                                               const float* __restrict__ bih,
                                               const float* __restrict__ bhh,
                                               int row, int quad, float scale) {
    Frag2 r;
#pragma unroll
    for (int j = 0; j < 8; ++j) { r.hi[j] = 0; r.lo[j] = 0; }
    if (quad == 0) {
        unsigned short h, l;
#pragma unroll
        for (int j = 0; j < FIN; ++j) {
            split_bf16(scale * Wih[row * FIN + j], h, l);
            r.hi[j] = (short)h; r.lo[j] = (short)l;
        }
        split_bf16(scale * (bih[row] + bhh[row]), h, l);
        r.hi[FIN] = (short)h; r.lo[FIN] = (short)l;
    }
    return r;
}

// stage one 64-step x chunk (bf16-hi, 1.0 in bias slot) into dst[64][SPB]
__device__ __forceinline__ void stage_chunk(const float* __restrict__ feat,
                                            bsh8 (*dst)[SPB],
                                            int seq0, int t0, int tid) {
#pragma unroll
    for (int it = 0; it < (64 * SPB) / BLK; ++it) {
        int idx = tid + it * BLK;
        int t2  = idx >> 4;
        int s   = idx & 15;
        const float* xp = feat + (size_t)(seq0 + s) * (TSTEPS * FIN) + (t0 + t2) * FIN;
        bsh8 v = {0, 0, 0, 0, 0, 0, 0, 0};
#pragma unroll
        for (int j = 0; j < FIN; ++j) v[j] = (short)bf16hi_rn(xp[j]);
        v[FIN] = (short)0x3F80;   // bf16(1.0) -> bias k-slot
        dst[t2][s] = v;
    }
}

// Two-element exp2-native LSTM cell epilogue with paired rcp:
//   trans = 5 exp2 + 1 rcp per element. rcp pairing: rcp(D0*D1), 1/D0 = R*D1.
__device__ __forceinline__ void epi2(float zi0, float zf0, float zg0, float zo0,
                                     float zi1, float zf1, float zg1, float zo1,
                                     float& cs0, float& cs1, float& h0, float& h1) {
    float Ei0 = __builtin_amdgcn_exp2f(zi0), Ei1 = __builtin_amdgcn_exp2f(zi1);
    float Ef0 = __builtin_amdgcn_exp2f(zf0), Ef1 = __builtin_amdgcn_exp2f(zf1);
    float Eg0 = __builtin_amdgcn_exp2f(zg0), Eg1 = __builtin_amdgcn_exp2f(zg1);
    float P10 = (1.0f + Ei0) * (1.0f + Eg0), Pf0 = 1.0f + Ef0;
    float P11 = (1.0f + Ei1) * (1.0f + Eg1), Pf1 = 1.0f + Ef1;
    float D0 = P10 * Pf0, D1 = P11 * Pf1;
    float Rp = __builtin_amdgcn_rcpf(D0 * D1);
    float n10 = __builtin_fmaf(SPOS, Eg0, -SPOS);
    float n11 = __builtin_fmaf(SPOS, Eg1, -SPOS);
    float m0 = __builtin_fmaf(P10, cs0, n10 * Pf0);
    float m1 = __builtin_fmaf(P11, cs1, n11 * Pf1);
    cs0 = (Rp * D1) * m0;          // sf*cs + SPOS*sig(i)*tanh(g)
    cs1 = (Rp * D0) * m1;
    float Eo0 = __builtin_amdgcn_exp2f(zo0), Eo1 = __builtin_amdgcn_exp2f(zo1);
    float Ec0 = __builtin_amdgcn_exp2f(cs0), Ec1 = __builtin_amdgcn_exp2f(cs1);
    float D20 = (1.0f + Eo0) * (1.0f + Ec0);
    float D21 = (1.0f + Eo1) * (1.0f + Ec1);
    float R2p = __builtin_amdgcn_rcpf(D20 * D21);
    h0 = (Ec0 - 1.0f) * (R2p * D21);   // sig(o)*tanh(c)
    h1 = (Ec1 - 1.0f) * (R2p * D20);
}

// R5 structure: dual-chain stagger. Chain A = seqs 0-7 (C quads 0-1),
// chain B = seqs 8-15 (C quads 2-3), independent LSTMs sharing one aA buffer
// (A owns rows 0-7, B owns rows 8-15). Per body(t), 2 phases:
//   P1: epi_A(t) trans  ||  MFMA_beta (gates_B(t), reads h_B(t-1) parity qA^1)
//   beta1
//   P2: epi_B(t) trans  ||  seedMFMA(t+1)  ||  MFMA_alpha (gates_A(t+1), parity qA)
//   beta2
// Every latency region (ds_read, MFMA, trans chains) has the other chain's
// independent work beside it IN THE SAME WAVE (ILP) — R4's lockstep fixed.
// Lane-dense per-chain epilogue (2 elem/lane) via one __shfl_xor(.,32)
// redistribution: quad<->quad^2 moves s[2],s[3] across the 32-lane boundary.
__global__ __launch_bounds__(BLK)
void lstm_kernel(const float* __restrict__ feat,
                 const float* __restrict__ Wih,
                 const float* __restrict__ Whh,
                 const float* __restrict__ bih,
                 const float* __restrict__ bhh,
                 const float* __restrict__ Wd,
                 const float* __restrict__ bd,
                 float* __restrict__ pred,
                 float* __restrict__ accums) {
    __shared__ bsh8  aA[2][SPB][9];                        // h bf16-hi, 2-parity
    __shared__ bsh8  xb[2][64][SPB];                       // x chunks (32 KB)
    __shared__ float hf[SPB][HID + 1];                     // final h fp32
    __shared__ float pf[SPB][17];                          // pred partials

    const int tid   = threadIdx.x;
    const int w     = tid >> 6;
    const int lane  = tid & 63;
    const int col   = lane & 15;       // MFMA col / A-row (seq)
    const int quad  = lane >> 4;
    const int u     = 16 * w + col;
    const int seq0  = blockIdx.x * SPB;

    if (blockIdx.x == 0 && tid < 4) accums[tid] = 0.0f;

    {
        bsh8 z = {0, 0, 0, 0, 0, 0, 0, 0};
        if (tid < SPB * 9) (&aA[1][0][0])[tid] = z;        // h(-1) = 0 (parity 1: B's first read)
    }
    stage_chunk(feat, xb[0], seq0, 0, tid);

    // ---- persistent B fragments (this wave handles its 16 units for BOTH chains) ----
    const Frag2 b00 = load_whh_frag(Whh, 0*HID + u,      quad*8, SNEG);
    const Frag2 b01 = load_whh_frag(Whh, 0*HID + u, 32 + quad*8, SNEG);
    const Frag2 b10 = load_whh_frag(Whh, 1*HID + u,      quad*8, SNEG);
    const Frag2 b11 = load_whh_frag(Whh, 1*HID + u, 32 + quad*8, SNEG);
    const Frag2 b20 = load_whh_frag(Whh, 2*HID + u,      quad*8, SPOS);
    const Frag2 b21 = load_whh_frag(Whh, 2*HID + u, 32 + quad*8, SPOS);
    const Frag2 b30 = load_whh_frag(Whh, 3*HID + u,      quad*8, SNEG);
    const Frag2 b31 = load_whh_frag(Whh, 3*HID + u, 32 + quad*8, SNEG);
    const Frag2 w0_ = load_wih_frag(Wih, bih, bhh, 0*HID + u, quad, SNEG);
    const Frag2 w1_ = load_wih_frag(Wih, bih, bhh, 1*HID + u, quad, SNEG);
    const Frag2 w2_ = load_wih_frag(Wih, bih, bhh, 2*HID + u, quad, SPOS);
    const Frag2 w3_ = load_wih_frag(Wih, bih, bhh, 3*HID + u, quad, SNEG);

    __syncthreads();   // xb[0] staged, aA[1] zeroed

    // prologue: seed(0) for both chains (rows 0-7 = A, 8-15 = B in one C frag)
    f32x4 sd0, sd1, sd2, sd3;
    {
        const f32x4 zz = {0.f, 0.f, 0.f, 0.f};
        bsh8 ax0 = xb[0][0][col];
        f32x4 e0 = MFMA16(ax0, w0_.hi, zz); e0 = MFMA16(ax0, w0_.lo, e0);
        f32x4 e1 = MFMA16(ax0, w1_.hi, zz); e1 = MFMA16(ax0, w1_.lo, e1);
        f32x4 e2 = MFMA16(ax0, w2_.hi, zz); e2 = MFMA16(ax0, w2_.lo, e2);
        f32x4 e3 = MFMA16(ax0, w3_.hi, zz); e3 = MFMA16(ax0, w3_.lo, e3);
        sd0 = e0; sd1 = e1; sd2 = e2; sd3 = e3;
    }

    f32x4 accA0 = {0.f,0.f,0.f,0.f}, accA1 = accA0, accA2 = accA0, accA3 = accA0; // h_A(-1)=0
    float csA0 = 0.f, csA1 = 0.f, csB0 = 0.f, csB1 = 0.f;

    // per-chain output rows for this lane (after quad<->quad^2 redistribution)
    const int rA = (quad & 1) * 4 + ((quad >> 1) ? 2 : 0);        // 0,4,2,6
    const int rB = 8 + (quad & 1) * 4 + ((quad >> 1) ? 0 : 2);     // 10,14,8,12
    unsigned short* const aAb = (unsigned short*)&aA[0][0][0];
    const int aAhalf = SPB * 9 * 8;        // shorts per parity buffer (row pitch 72)

    for (int t = 0; t < TSTEPS; ++t) {
        const int  qA   = t & 1;
        const bool have = (t + 1 < TSTEPS);
        const f32x4 zz  = {0.f, 0.f, 0.f, 0.f};

        // ================= phase 1 =================
        // issue loads early: frag for MFMA_beta (h_B(t-1)) + x for seed(t+1)
        bsh8 fB0 = aA[qA ^ 1][col][quad];
        bsh8 fB1 = aA[qA ^ 1][col][4 + quad];
        bsh8 ax  = xb[((t + 1) >> 6) & 1][(t + 1) & 63][col];   // safe read even at t=T-1

        // ---- epi_A(t): chain A, lane-dense via shfl_xor 32 ----
        f32x4 sA0 = accA0 + sd0, sA1 = accA1 + sd1, sA2 = accA2 + sd2, sA3 = accA3 + sd3;
        float xi0 = __shfl_xor(sA0[2], 32, 64), xi1 = __shfl_xor(sA0[3], 32, 64);
        float xf0 = __shfl_xor(sA1[2], 32, 64), xf1 = __shfl_xor(sA1[3], 32, 64);
        float xg0 = __shfl_xor(sA2[2], 32, 64), xg1 = __shfl_xor(sA2[3], 32, 64);
        float xo0 = __shfl_xor(sA3[2], 32, 64), xo1 = __shfl_xor(sA3[3], 32, 64);
        const bool loq = (quad < 2);
        float zi0 = loq ? sA0[0] : xi0, zi1 = loq ? sA0[1] : xi1;
        float zf0 = loq ? sA1[0] : xf0, zf1 = loq ? sA1[1] : xf1;
        float zg0 = loq ? sA2[0] : xg0, zg1 = loq ? sA2[1] : xg1;
        float zo0 = loq ? sA3[0] : xo0, zo1 = loq ? sA3[1] : xo1;

        // ---- MFMA_beta: gates_B(t) (C rows 8-15 valid; rows 0-7 discarded) ----
        f32x4 accB0 = MFMA16(fB0, b00.hi, zz);
        f32x4 accB1 = MFMA16(fB0, b10.hi, zz);
        f32x4 accB2 = MFMA16(fB0, b20.hi, zz);
        f32x4 accB3 = MFMA16(fB0, b30.hi, zz);
        accB0 = MFMA16(fB1, b01.hi, accB0);
        accB1 = MFMA16(fB1, b11.hi, accB1);
        accB2 = MFMA16(fB1, b21.hi, accB2);
        accB3 = MFMA16(fB1, b31.hi, accB3);
        accB0 = MFMA16(fB0, b00.lo, accB0);
        accB1 = MFMA16(fB0, b10.lo, accB1);
        accB2 = MFMA16(fB0, b20.lo, accB2);
        accB3 = MFMA16(fB0, b30.lo, accB3);
        accB0 = MFMA16(fB1, b01.lo, accB0);
        accB1 = MFMA16(fB1, b11.lo, accB1);
        accB2 = MFMA16(fB1, b21.lo, accB2);
        accB3 = MFMA16(fB1, b31.lo, accB3);

        float hA0, hA1;
        epi2(zi0, zf0, zg0, zo0, zi1, zf1, zg1, zo1, csA0, csA1, hA0, hA1);
        {
            unsigned pk;
            asm("v_cvt_pk_bf16_f32 %0, %1, %2" : "=v"(pk) : "v"(hA0), "v"(hA1));
            unsigned short* hp = aAb + qA * aAhalf + rA * 72 + u;
            hp[0]  = (unsigned short)pk;
            hp[72] = (unsigned short)(pk >> 16);
        }
        if (t == TSTEPS - 1) { hf[rA][u] = hA0; hf[rA + 1][u] = hA1; }

        if ((t & 63) == 0 && t + 64 < TSTEPS)
            stage_chunk(feat, xb[((t >> 6) + 1) & 1], seq0, ((t >> 6) + 1) * 64, tid);

        __syncthreads();   // beta1: h_A(t) visible

        // ================= phase 2 =================
        bsh8 fA0 = aA[qA][col][quad];          // rows 0-7 = h_A(t) fresh
        bsh8 fA1 = aA[qA][col][4 + quad];

        // ---- epi_B(t) inputs: chain B (quads 2-3 own, quads 0-1 via shfl) ----
        f32x4 sB0 = accB0 + sd0, sB1 = accB1 + sd1, sB2 = accB2 + sd2, sB3 = accB3 + sd3;
        float yi0 = __shfl_xor(sB0[2], 32, 64), yi1 = __shfl_xor(sB0[3], 32, 64);
        float yf0 = __shfl_xor(sB1[2], 32, 64), yf1 = __shfl_xor(sB1[3], 32, 64);
        float yg0 = __shfl_xor(sB2[2], 32, 64), yg1 = __shfl_xor(sB2[3], 32, 64);
        float yo0 = __shfl_xor(sB3[2], 32, 64), yo1 = __shfl_xor(sB3[3], 32, 64);
        const bool hiq = (quad >= 2);
        float wi0 = hiq ? sB0[0] : yi0, wi1 = hiq ? sB0[1] : yi1;
        float wf0 = hiq ? sB1[0] : yf0, wf1 = hiq ? sB1[1] : yf1;
        float wg0 = hiq ? sB2[0] : yg0, wg1 = hiq ? sB2[1] : yg1;
        float wo0 = hiq ? sB3[0] : yo0, wo1 = hiq ? sB3[1] : yo1;

        // ---- seedMFMA(t+1) -> sd (sd fully consumed by sA/sB above) ----
        if (have) {
            f32x4 e0 = MFMA16(ax, w0_.hi, zz); e0 = MFMA16(ax, w0_.lo, e0);
            f32x4 e1 = MFMA16(ax, w1_.hi, zz); e1 = MFMA16(ax, w1_.lo, e1);
            f32x4 e2 = MFMA16(ax, w2_.hi, zz); e2 = MFMA16(ax, w2_.lo, e2);
            f32x4 e3 = MFMA16(ax, w3_.hi, zz); e3 = MFMA16(ax, w3_.lo, e3);
            sd0 = e0; sd1 = e1; sd2 = e2; sd3 = e3;
        }

        // ---- MFMA_alpha: gates_A(t+1) from h_A(t) (rows 0-7 valid) ----
        if (have) {
            accA0 = MFMA16(fA0, b00.hi, zz);
            accA1 = MFMA16(fA0, b10.hi, zz);
            accA2 = MFMA16(fA0, b20.hi, zz);
            accA3 = MFMA16(fA0, b30.hi, zz);
            accA0 = MFMA16(fA1, b01.hi, accA0);
            accA1 = MFMA16(fA1, b11.hi, accA1);
            accA2 = MFMA16(fA1, b21.hi, accA2);
            accA3 = MFMA16(fA1, b31.hi, accA3);
            accA0 = MFMA16(fA0, b00.lo, accA0);
            accA1 = MFMA16(fA0, b10.lo, accA1);
            accA2 = MFMA16(fA0, b20.lo, accA2);
            accA3 = MFMA16(fA0, b30.lo, accA3);
            accA0 = MFMA16(fA1, b01.lo, accA0);
            accA1 = MFMA16(fA1, b11.lo, accA1);
            accA2 = MFMA16(fA1, b21.lo, accA2);
            accA3 = MFMA16(fA1, b31.lo, accA3);
        }

        float hB0, hB1;
        epi2(wi0, wf0, wg0, wo0, wi1, wf1, wg1, wo1, csB0, csB1, hB0, hB1);
        {
            unsigned pk;
            asm("v_cvt_pk_bf16_f32 %0, %1, %2" : "=v"(pk) : "v"(hB0), "v"(hB1));
            unsigned short* hp = aAb + qA * aAhalf + rB * 72 + u;
            hp[0]  = (unsigned short)pk;
            hp[72] = (unsigned short)(pk >> 16);
        }
        if (t == TSTEPS - 1) { hf[rB][u] = hB0; hf[rB + 1][u] = hB1; }

        __syncthreads();   // beta2: h_B(t) visible
    }

    // ---- fused pred head: pred = leaky_relu(h @ Wd^T + bd) ----
    {
        int s  = tid & 15;
        int hq = tid >> 4;           // 16 unit-groups of 4
        int j0 = hq * 4;
        float part = hf[s][j0] * Wd[j0] + hf[s][j0 + 1] * Wd[j0 + 1]
                   + hf[s][j0 + 2] * Wd[j0 + 2] + hf[s][j0 + 3] * Wd[j0 + 3];
        pf[s][hq] = part;
    }
    __syncthreads();
    if (tid < SPB) {
        float sum = bd[0];
#pragma unroll
        for (int j = 0; j < 16; ++j) sum += pf[tid][j];
        float p = (sum >= 0.0f) ? sum : 0.2f * sum;
        pred[seq0 + tid] = p;
    }
}

// fused losses: grid 512 (2 blocks/CU), 8 i-rows per block, f32x4 LDS reads.
// block 0 additionally does the masked-MSE partials.
__global__ __launch_bounds__(256)
void loss_kernel(const float* __restrict__ pred,
                 const float* __restrict__ ret,
                 const int* __restrict__ mask,
                 float* __restrict__ accums) {
    __shared__ __align__(16) float sp[NSEQ];
    __shared__ __align__(16) float sg_[NSEQ];
    __shared__ __align__(16) float sq[NSEQ];
    __shared__ float wsum[8];
    int tid = threadIdx.x;
    for (int idx = tid; idx < NSEQ / 4; idx += 256) {
        f32x4 p4 = ((const f32x4*)pred)[idx];
        f32x4 g4 = ((const f32x4*)ret)[idx];
        i32x4 m4 = ((const i32x4*)mask)[idx];
        f32x4 q4;
#pragma unroll
        for (int l = 0; l < 4; ++l) q4[l] = m4[l] ? 1.0f : 0.0f;
        *(f32x4*)&sp[idx * 4] = p4;
        *(f32x4*)&sg_[idx * 4] = g4;
        *(f32x4*)&sq[idx * 4] = q4;
    }
    __syncthreads();

    if (blockIdx.x == 0) {   // regression loss partials
        float v = 0.0f, m = 0.0f;
        for (int j = tid; j < NSEQ; j += 256) {
            float mj = sq[j];
            float d  = sp[j] - sg_[j];
            v += d * d * mj;
            m += mj;
        }
#pragma unroll
        for (int off = 32; off > 0; off >>= 1) {
            v += __shfl_down(v, off, 64);
            m += __shfl_down(m, off, 64);
        }
        if ((tid & 63) == 0) {
            atomicAdd(&accums[0], v);
            atomicAdd(&accums[1], m);
        }
    }

    int iloc = tid >> 5;          // 8 rows per block
    int jp   = tid & 31;          // 32 lanes per row
    int i    = blockIdx.x * 8 + iloc;
    float pi = sp[i], gi = sg_[i], qi = sq[i];
    float sum = 0.0f;
    for (int j0 = jp * 4; j0 < NSEQ; j0 += 128) {
        f32x4 p4 = *(const f32x4*)&sp[j0];
        f32x4 g4 = *(const f32x4*)&sg_[j0];
        f32x4 q4 = *(const f32x4*)&sq[j0];
#pragma unroll
        for (int l = 0; l < 4; ++l) {
            float t = -(p4[l] - pi) * (g4[l] - gi);
            sum += fmaxf(t, 0.0f) * q4[l];
        }
    }
    sum *= qi;
#pragma unroll
    for (int off = 16; off > 0; off >>= 1) sum += __shfl_down(sum, off, 32);
    if (jp == 0) wsum[iloc] = sum;
    __syncthreads();
    if (tid == 0) {
        float s = wsum[0] + wsum[1] + wsum[2] + wsum[3]
                + wsum[4] + wsum[5] + wsum[6] + wsum[7];
        atomicAdd(&accums[2], s);
    }
}

__global__ void final_kernel(const float* __restrict__ accums,
                             float* __restrict__ out) {
    float reg  = accums[0] / (accums[1] + 1e-8f);
    float rank = accums[2] / 16777216.0f;   // N*N
    out[NSEQ + 0] = reg + rank;
    out[NSEQ + 1] = reg;
    out[NSEQ + 2] = rank;
}

extern "C" void kernel_launch(void* const* d_in, const int* in_sizes, int n_in,
                              void* d_out, int out_size, void* d_ws, size_t ws_size,
                              hipStream_t stream) {
    const float* feat = (const float*)d_in[0];
    const float* ret  = (const float*)d_in[1];
    const int*   mask = (const int*)d_in[2];
    const float* Wih  = (const float*)d_in[3];
    const float* Whh  = (const float*)d_in[4];
    const float* bih  = (const float*)d_in[5];
    const float* bhh  = (const float*)d_in[6];
    const float* Wd   = (const float*)d_in[7];
    const float* bd   = (const float*)d_in[8];
    float* out    = (float*)d_out;
    float* accums = (float*)d_ws;            // [0..3] loss partials

    lstm_kernel<<<NSEQ / SPB, BLK, 0, stream>>>(feat, Wih, Whh, bih, bhh,
                                                Wd, bd, out, accums);
    loss_kernel<<<NSEQ / 8, 256, 0, stream>>>(out, ret, mask, accums);
    final_kernel<<<1, 1, 0, stream>>>(accums, out);
}

// Round 6
// 467.024 us; speedup vs baseline: 1.2384x; 1.2384x over previous
//
#include <hip/hip_runtime.h>

#define NSEQ   4096
#define TSTEPS 512
#define FIN    5
#define HID    64
#define SPB    8      // sequences per block — 512 blocks -> 2 blocks/CU (TLP)
#define BLK    512    // 8 waves: w0-3 "G" (gate MFMA + dense epilogue), w4-7 "E" (seed + staging)

// Neutral names — do NOT reuse HIP vector-type names like short8 (R4 crash)
typedef __attribute__((ext_vector_type(8))) short bsh8;    // 8 bf16 in 4 VGPRs
typedef __attribute__((ext_vector_type(4))) float f32x4;   // MFMA accumulator
typedef __attribute__((ext_vector_type(2))) float f32x2;
typedef __attribute__((ext_vector_type(4))) int   i32x4;

#define MFMA16(A, B, C) __builtin_amdgcn_mfma_f32_16x16x32_bf16((A), (B), (C), 0, 0, 0)

// Gate pre-scaling folded into weights/biases so MFMA output is exp2-ready.
//   i,f,o rows scaled by -log2e  -> sigmoid = rcp(1 + exp2(m))
//   g rows scaled by +2*log2e    -> tanh    = (Eg-1)/(Eg+1)
//   c tracked as cs = 2*log2e*c  -> tanh(c) = (Ec-1)/(Ec+1)
#define LOG2E 1.4426950408889634f
#define SNEG  (-LOG2E)
#define SPOS  (2.0f * LOG2E)

struct Frag2 { bsh8 hi; bsh8 lo; };

__device__ __forceinline__ unsigned short bf16hi_rn(float x) {
    unsigned u = __float_as_uint(x);
    return (unsigned short)((u + 0x7fffu + ((u >> 16) & 1u)) >> 16);
}
__device__ __forceinline__ void split_bf16(float v, unsigned short& h, unsigned short& l) {
    h = bf16hi_rn(v);
    float hf_ = __uint_as_float(((unsigned)h) << 16);
    l = bf16hi_rn(v - hf_);
}

__device__ __forceinline__ Frag2 load_whh_frag(const float* __restrict__ Whh, int row, int k, float scale) {
    const float* p = Whh + row * HID + k;
    Frag2 r;
#pragma unroll
    for (int j = 0; j < 8; ++j) {
        unsigned short h, l;
        split_bf16(scale * p[j], h, l);
        r.hi[j] = (short)h; r.lo[j] = (short)l;
    }
    return r;
}
__device__ __forceinline__ Frag2 load_wih_frag(const float* __restrict__ Wih,
                                               const float* __restrict__ bih,
                                               const float* __restrict__ bhh,
                                               int row, int quad, float scale) {
    Frag2 r;
#pragma unroll
    for (int j = 0; j < 8; ++j) { r.hi[j] = 0; r.lo[j] = 0; }
    if (quad == 0) {
        unsigned short h, l;
#pragma unroll
        for (int j = 0; j < FIN; ++j) {
            split_bf16(scale * Wih[row * FIN + j], h, l);
            r.hi[j] = (short)h; r.lo[j] = (short)l;
        }
        split_bf16(scale * (bih[row] + bhh[row]), h, l);
        r.hi[FIN] = (short)h; r.lo[FIN] = (short)l;
    }
    return r;
}

// stage one 64-step x chunk (bf16-hi, 1.0 in bias slot) into dst[64][16]
// (cols 0-7 only; cols 8-15 are permanent zero pad) — E-waves (256 thr)
__device__ __forceinline__ void stage_chunk(const float* __restrict__ feat,
                                            bsh8 (*dst)[16],
                                            int seq0, int t0, int tidE) {
#pragma unroll
    for (int it = 0; it < (64 * SPB) / 256; ++it) {
        int idx = tidE + it * 256;
        int t2  = idx >> 3;
        int s   = idx & 7;
        const float* xp = feat + (size_t)(seq0 + s) * (TSTEPS * FIN) + (t0 + t2) * FIN;
        bsh8 v = {0, 0, 0, 0, 0, 0, 0, 0};
#pragma unroll
        for (int j = 0; j < FIN; ++j) v[j] = (short)bf16hi_rn(xp[j]);
        v[FIN] = (short)0x3F80;   // bf16(1.0) -> bias k-slot
        dst[t2][s] = v;
    }
}

// Two-element exp2-native LSTM cell epilogue with paired rcp:
//   trans = 5 exp2 + 1 rcp per element (12 wave-instrs for 2 elems).
//   rcp pairing: rcp(D0*D1), then 1/D0 = R*D1. cs is c in 2*log2e scale.
__device__ __forceinline__ void epi2(float zi0, float zf0, float zg0, float zo0,
                                     float zi1, float zf1, float zg1, float zo1,
                                     float& cs0, float& cs1, float& h0, float& h1) {
    float Ei0 = __builtin_amdgcn_exp2f(zi0), Ei1 = __builtin_amdgcn_exp2f(zi1);
    float Ef0 = __builtin_amdgcn_exp2f(zf0), Ef1 = __builtin_amdgcn_exp2f(zf1);
    float Eg0 = __builtin_amdgcn_exp2f(zg0), Eg1 = __builtin_amdgcn_exp2f(zg1);
    float P10 = (1.0f + Ei0) * (1.0f + Eg0), Pf0 = 1.0f + Ef0;
    float P11 = (1.0f + Ei1) * (1.0f + Eg1), Pf1 = 1.0f + Ef1;
    float D0 = P10 * Pf0, D1 = P11 * Pf1;
    float Rp = __builtin_amdgcn_rcpf(D0 * D1);
    float n10 = __builtin_fmaf(SPOS, Eg0, -SPOS);
    float n11 = __builtin_fmaf(SPOS, Eg1, -SPOS);
    float m0 = __builtin_fmaf(P10, cs0, n10 * Pf0);
    float m1 = __builtin_fmaf(P11, cs1, n11 * Pf1);
    cs0 = (Rp * D1) * m0;          // sf*cs + SPOS*sig(i)*tanh(g)
    cs1 = (Rp * D0) * m1;
    float Eo0 = __builtin_amdgcn_exp2f(zo0), Eo1 = __builtin_amdgcn_exp2f(zo1);
    float Ec0 = __builtin_amdgcn_exp2f(cs0), Ec1 = __builtin_amdgcn_exp2f(cs1);
    float D20 = (1.0f + Eo0) * (1.0f + Ec0);
    float D21 = (1.0f + Eo1) * (1.0f + Ec1);
    float R2p = __builtin_amdgcn_rcpf(D20 * D21);
    h0 = (Ec0 - 1.0f) * (R2p * D21);   // sig(o)*tanh(c)
    h1 = (Ec1 - 1.0f) * (R2p * D20);
}

// R6 structure: R2's proven G/E wave-split + 1 barrier/step, at SPB=8 so the
// grid is 512 blocks -> 2 independent blocks per CU (4 waves/SIMD: 2 G + 2 E
// from DIFFERENT blocks). Independent blocks have independent barriers, so
// one block's stall (barrier drain, ds_read, exp2 chain) is filled by the
// other block's issue — the ~700 cyc/step of dead time R2's counters showed.
// The 8 valid C-rows are made lane-dense for the epilogue via __shfl_xor 32
// (quads 2,3 take rows {2,3},{6,7}): whole epilogue = ONE epi2 = 12 trans
// instrs/step (R2: 32). Seeds ride a lane-linear f32x2 mailbox (conflict-free).
__global__ __launch_bounds__(BLK, 4)
void lstm_kernel(const float* __restrict__ feat,
                 const float* __restrict__ Wih,
                 const float* __restrict__ Whh,
                 const float* __restrict__ bih,
                 const float* __restrict__ bhh,
                 const float* __restrict__ Wd,
                 const float* __restrict__ bd,
                 float* __restrict__ pred,
                 float* __restrict__ accums) {
    __shared__ bsh8  aA[2][16][9];                         // h bf16-hi (rows 8-15 perm. zero)
    __shared__ bsh8  xb[2][64][16];                        // x chunks, cols 8-15 zero pad (32 KB)
    __shared__ __align__(8) f32x2 sg[2][4][4][64];         // seed pairs [parity][w][gate][lane] (16 KB)
    __shared__ float hf[SPB][HID + 1];                     // final h fp32
    __shared__ float pf[SPB][17];                          // pred partials

    const int tid   = threadIdx.x;
    const int w     = tid >> 6;
    const int lane  = tid & 63;
    const int col   = lane & 15;       // MFMA col / A-row (seq)
    const int quad  = lane >> 4;
    const int seq0  = blockIdx.x * SPB;

    if (blockIdx.x == 0 && tid < 4) accums[tid] = 0.0f;

    {   // zero aA (both parities, all rows — rows 8-15 stay zero forever)
        bsh8 z = {0, 0, 0, 0, 0, 0, 0, 0};
        if (tid < 2 * 16 * 9) (&aA[0][0][0])[tid] = z;
        // zero xb cols 8-15 (both buffers) — staging never touches them
#pragma unroll
        for (int k = 0; k < 2; ++k) {
            int i  = tid + k * BLK;            // 1024 items
            int b  = i >> 9;
            int t2 = (i >> 3) & 63;
            int s8 = 8 + (i & 7);
            xb[b][t2][s8] = z;
        }
    }
    if (w >= 4) stage_chunk(feat, xb[0], seq0, 0, tid - 256);

    // lane-dense epilogue row mapping (quads 0..3 -> base rows 0,4,2,6)
    const int rA  = (quad & 1) * 4 + ((quad >> 1) ? 2 : 0);
    const bool loq = (quad < 2);

    if (w < 4) {
        // ---------------- G-waves: h-MFMA + dense epilogue ----------------
        const int u = 16 * w + col;
        const Frag2 b00 = load_whh_frag(Whh, 0*HID + u,      quad*8, SNEG);
        const Frag2 b01 = load_whh_frag(Whh, 0*HID + u, 32 + quad*8, SNEG);
        const Frag2 b10 = load_whh_frag(Whh, 1*HID + u,      quad*8, SNEG);
        const Frag2 b11 = load_whh_frag(Whh, 1*HID + u, 32 + quad*8, SNEG);
        const Frag2 b20 = load_whh_frag(Whh, 2*HID + u,      quad*8, SPOS);
        const Frag2 b21 = load_whh_frag(Whh, 2*HID + u, 32 + quad*8, SPOS);
        const Frag2 b30 = load_whh_frag(Whh, 3*HID + u,      quad*8, SNEG);
        const Frag2 b31 = load_whh_frag(Whh, 3*HID + u, 32 + quad*8, SNEG);

        __syncthreads();   // init + xb[0] staged

        float cs0 = 0.f, cs1 = 0.f;    // c (2*log2e scale) for rows rA, rA+1
        unsigned short* const aAb = (unsigned short*)&aA[0][0][0];
        const int rowbase = rA * 72 + u;       // aA row pitch = 72 shorts
        const int aAhalf  = 16 * 9 * 8;        // shorts per parity buffer
        __builtin_amdgcn_s_setprio(1);         // T5: favor the critical wave

        for (int t = 0; t < TSTEPS; ++t) {
            const int buf = t & 1;
            const int nb  = buf ^ 1;
            __syncthreads();   // h(t-1) + sg[buf] visible

            bsh8 ah0 = aA[buf][col][quad];
            bsh8 ah1 = aA[buf][col][4 + quad];
            f32x2 s0 = sg[buf][w][0][lane];    // issued early, consumed post-MFMA
            f32x2 s1 = sg[buf][w][1][lane];
            f32x2 s2 = sg[buf][w][2][lane];
            f32x2 s3 = sg[buf][w][3][lane];

            const f32x4 zz = {0.f, 0.f, 0.f, 0.f};
            f32x4 acc0 = MFMA16(ah0, b00.hi, zz);
            f32x4 acc1 = MFMA16(ah0, b10.hi, zz);
            f32x4 acc2 = MFMA16(ah0, b20.hi, zz);
            f32x4 acc3 = MFMA16(ah0, b30.hi, zz);
            acc0 = MFMA16(ah1, b01.hi, acc0);
            acc1 = MFMA16(ah1, b11.hi, acc1);
            acc2 = MFMA16(ah1, b21.hi, acc2);
            acc3 = MFMA16(ah1, b31.hi, acc3);
            acc0 = MFMA16(ah0, b00.lo, acc0);
            acc1 = MFMA16(ah0, b10.lo, acc1);
            acc2 = MFMA16(ah0, b20.lo, acc2);
            acc3 = MFMA16(ah0, b30.lo, acc3);
            acc0 = MFMA16(ah1, b01.lo, acc0);
            acc1 = MFMA16(ah1, b11.lo, acc1);
            acc2 = MFMA16(ah1, b21.lo, acc2);
            acc3 = MFMA16(ah1, b31.lo, acc3);

            // dense redistribution: quads 2,3 take rows {2,3},{6,7} from quads 0,1
            float x00 = __shfl_xor(acc0[2], 32, 64), x01 = __shfl_xor(acc0[3], 32, 64);
            float x10 = __shfl_xor(acc1[2], 32, 64), x11 = __shfl_xor(acc1[3], 32, 64);
            float x20 = __shfl_xor(acc2[2], 32, 64), x21 = __shfl_xor(acc2[3], 32, 64);
            float x30 = __shfl_xor(acc3[2], 32, 64), x31 = __shfl_xor(acc3[3], 32, 64);
            float zi0 = (loq ? acc0[0] : x00) + s0.x, zi1 = (loq ? acc0[1] : x01) + s0.y;
            float zf0 = (loq ? acc1[0] : x10) + s1.x, zf1 = (loq ? acc1[1] : x11) + s1.y;
            float zg0 = (loq ? acc2[0] : x20) + s2.x, zg1 = (loq ? acc2[1] : x21) + s2.y;
            float zo0 = (loq ? acc3[0] : x30) + s3.x, zo1 = (loq ? acc3[1] : x31) + s3.y;

            float h0, h1;
            epi2(zi0, zf0, zg0, zo0, zi1, zf1, zg1, zo1, cs0, cs1, h0, h1);
            unsigned pk;
            asm("v_cvt_pk_bf16_f32 %0, %1, %2" : "=v"(pk) : "v"(h0), "v"(h1));
            unsigned short* hp = aAb + nb * aAhalf + rowbase;
            hp[0]  = (unsigned short)pk;          // row rA
            hp[72] = (unsigned short)(pk >> 16);  // row rA+1
            if (t == TSTEPS - 1) {
                hf[rA + 0][u] = h0;
                hf[rA + 1][u] = h1;
            }
        }
        __builtin_amdgcn_s_setprio(0);
    } else {
        // ---------------- E-waves: x-projection seed + staging ----------------
        const int wE   = w - 4;
        const int tidE = tid - 256;
        const int uE   = 16 * wE + col;
        const Frag2 w0 = load_wih_frag(Wih, bih, bhh, 0*HID + uE, quad, SNEG);
        const Frag2 w1 = load_wih_frag(Wih, bih, bhh, 1*HID + uE, quad, SNEG);
        const Frag2 w2 = load_wih_frag(Wih, bih, bhh, 2*HID + uE, quad, SPOS);
        const Frag2 w3 = load_wih_frag(Wih, bih, bhh, 3*HID + uE, quad, SNEG);

        __syncthreads();   // init + xb[0] staged

        {   // seed(0) -> sg[0] (before first in-loop barrier)
            bsh8 ax = xb[0][0][col];
            f32x4 e0 = {0.f,0.f,0.f,0.f}, e1 = e0, e2 = e0, e3 = e0;
            e0 = MFMA16(ax, w0.hi, e0); e0 = MFMA16(ax, w0.lo, e0);
            e1 = MFMA16(ax, w1.hi, e1); e1 = MFMA16(ax, w1.lo, e1);
            e2 = MFMA16(ax, w2.hi, e2); e2 = MFMA16(ax, w2.lo, e2);
            e3 = MFMA16(ax, w3.hi, e3); e3 = MFMA16(ax, w3.lo, e3);
            float x0 = __shfl_xor(e0[2], 32, 64), x0b = __shfl_xor(e0[3], 32, 64);
            float x1 = __shfl_xor(e1[2], 32, 64), x1b = __shfl_xor(e1[3], 32, 64);
            float x2 = __shfl_xor(e2[2], 32, 64), x2b = __shfl_xor(e2[3], 32, 64);
            float x3 = __shfl_xor(e3[2], 32, 64), x3b = __shfl_xor(e3[3], 32, 64);
            sg[0][wE][0][lane] = (f32x2){loq ? e0[0] : x0, loq ? e0[1] : x0b};
            sg[0][wE][1][lane] = (f32x2){loq ? e1[0] : x1, loq ? e1[1] : x1b};
            sg[0][wE][2][lane] = (f32x2){loq ? e2[0] : x2, loq ? e2[1] : x2b};
            sg[0][wE][3][lane] = (f32x2){loq ? e3[0] : x3, loq ? e3[1] : x3b};
        }
        for (int t = 0; t < TSTEPS; ++t) {
            __syncthreads();   // matches G's per-step barrier
            if ((t & 63) == 0 && t + 64 < TSTEPS)
                stage_chunk(feat, xb[((t >> 6) + 1) & 1], seq0, ((t >> 6) + 1) * 64, tidE);
            if (t + 1 < TSTEPS) {
                const int t1 = t + 1;
                bsh8 ax = xb[(t1 >> 6) & 1][t1 & 63][col];
                f32x4 e0 = {0.f,0.f,0.f,0.f}, e1 = e0, e2 = e0, e3 = e0;
                e0 = MFMA16(ax, w0.hi, e0); e0 = MFMA16(ax, w0.lo, e0);
                e1 = MFMA16(ax, w1.hi, e1); e1 = MFMA16(ax, w1.lo, e1);
                e2 = MFMA16(ax, w2.hi, e2); e2 = MFMA16(ax, w2.lo, e2);
                e3 = MFMA16(ax, w3.hi, e3); e3 = MFMA16(ax, w3.lo, e3);
                float x0 = __shfl_xor(e0[2], 32, 64), x0b = __shfl_xor(e0[3], 32, 64);
                float x1 = __shfl_xor(e1[2], 32, 64), x1b = __shfl_xor(e1[3], 32, 64);
                float x2 = __shfl_xor(e2[2], 32, 64), x2b = __shfl_xor(e2[3], 32, 64);
                float x3 = __shfl_xor(e3[2], 32, 64), x3b = __shfl_xor(e3[3], 32, 64);
                const int sb = t1 & 1;
                sg[sb][wE][0][lane] = (f32x2){loq ? e0[0] : x0, loq ? e0[1] : x0b};
                sg[sb][wE][1][lane] = (f32x2){loq ? e1[0] : x1, loq ? e1[1] : x1b};
                sg[sb][wE][2][lane] = (f32x2){loq ? e2[0] : x2, loq ? e2[1] : x2b};
                sg[sb][wE][3][lane] = (f32x2){loq ? e3[0] : x3, loq ? e3[1] : x3b};
            }
        }
    }
    __syncthreads();   // hf visible

    // ---- fused pred head: pred = leaky_relu(h @ Wd^T + bd) ----
    if (tid < 8 * 16) {
        int s  = tid & 7;
        int hq = tid >> 3;           // 16 unit-groups of 4
        int j0 = hq * 4;
        float part = hf[s][j0] * Wd[j0] + hf[s][j0 + 1] * Wd[j0 + 1]
                   + hf[s][j0 + 2] * Wd[j0 + 2] + hf[s][j0 + 3] * Wd[j0 + 3];
        pf[s][hq] = part;
    }
    __syncthreads();
    if (tid < SPB) {
        float sum = bd[0];
#pragma unroll
        for (int j = 0; j < 16; ++j) sum += pf[tid][j];
        float p = (sum >= 0.0f) ? sum : 0.2f * sum;
        pred[seq0 + tid] = p;
    }
}

// fused losses: grid 512 (2 blocks/CU), 8 i-rows per block, f32x4 LDS reads.
// block 0 additionally does the masked-MSE partials.
__global__ __launch_bounds__(256)
void loss_kernel(const float* __restrict__ pred,
                 const float* __restrict__ ret,
                 const int* __restrict__ mask,
                 float* __restrict__ accums) {
    __shared__ __align__(16) float sp[NSEQ];
    __shared__ __align__(16) float sg_[NSEQ];
    __shared__ __align__(16) float sq[NSEQ];
    __shared__ float wsum[8];
    int tid = threadIdx.x;
    for (int idx = tid; idx < NSEQ / 4; idx += 256) {
        f32x4 p4 = ((const f32x4*)pred)[idx];
        f32x4 g4 = ((const f32x4*)ret)[idx];
        i32x4 m4 = ((const i32x4*)mask)[idx];
        f32x4 q4;
#pragma unroll
        for (int l = 0; l < 4; ++l) q4[l] = m4[l] ? 1.0f : 0.0f;
        *(f32x4*)&sp[idx * 4] = p4;
        *(f32x4*)&sg_[idx * 4] = g4;
        *(f32x4*)&sq[idx * 4] = q4;
    }
    __syncthreads();

    if (blockIdx.x == 0) {   // regression loss partials
        float v = 0.0f, m = 0.0f;
        for (int j = tid; j < NSEQ; j += 256) {
            float mj = sq[j];
            float d  = sp[j] - sg_[j];
            v += d * d * mj;
            m += mj;
        }
#pragma unroll
        for (int off = 32; off > 0; off >>= 1) {
            v += __shfl_down(v, off, 64);
            m += __shfl_down(m, off, 64);
        }
        if ((tid & 63) == 0) {
            atomicAdd(&accums[0], v);
            atomicAdd(&accums[1], m);
        }
    }

    int iloc = tid >> 5;          // 8 rows per block
    int jp   = tid & 31;          // 32 lanes per row
    int i    = blockIdx.x * 8 + iloc;
    float pi = sp[i], gi = sg_[i], qi = sq[i];
    float sum = 0.0f;
    for (int j0 = jp * 4; j0 < NSEQ; j0 += 128) {
        f32x4 p4 = *(const f32x4*)&sp[j0];
        f32x4 g4 = *(const f32x4*)&sg_[j0];
        f32x4 q4 = *(const f32x4*)&sq[j0];
#pragma unroll
        for (int l = 0; l < 4; ++l) {
            float t = -(p4[l] - pi) * (g4[l] - gi);
            sum += fmaxf(t, 0.0f) * q4[l];
        }
    }
    sum *= qi;
#pragma unroll
    for (int off = 16; off > 0; off >>= 1) sum += __shfl_down(sum, off, 32);
    if (jp == 0) wsum[iloc] = sum;
    __syncthreads();
    if (tid == 0) {
        float s = wsum[0] + wsum[1] + wsum[2] + wsum[3]
                + wsum[4] + wsum[5] + wsum[6] + wsum[7];
        atomicAdd(&accums[2], s);
    }
}

__global__ void final_kernel(const float* __restrict__ accums,
                             float* __restrict__ out) {
    float reg  = accums[0] / (accums[1] + 1e-8f);
    float rank = accums[2] / 16777216.0f;   // N*N
    out[NSEQ + 0] = reg + rank;
    out[NSEQ + 1] = reg;
    out[NSEQ + 2] = rank;
}

extern "C" void kernel_launch(void* const* d_in, const int* in_sizes, int n_in,
                              void* d_out, int out_size, void* d_ws, size_t ws_size,
                              hipStream_t stream) {
    const float* feat = (const float*)d_in[0];
    const float* ret  = (const float*)d_in[1];
    const int*   mask = (const int*)d_in[2];
    const float* Wih  = (const float*)d_in[3];
    const float* Whh  = (const float*)d_in[4];
    const float* bih  = (const float*)d_in[5];
    const float* bhh  = (const float*)d_in[6];
    const float* Wd   = (const float*)d_in[7];
    const float* bd   = (const float*)d_in[8];
    float* out    = (float*)d_out;
    float* accums = (float*)d_ws;            // [0..3] loss partials

    lstm_kernel<<<NSEQ / SPB, BLK, 0, stream>>>(feat, Wih, Whh, bih, bhh,
                                                Wd, bd, out, accums);
    loss_kernel<<<NSEQ / 8, 256, 0, stream>>>(out, ret, mask, accums);
    final_kernel<<<1, 1, 0, stream>>>(accums, out);
}

// Round 7
// 460.722 us; speedup vs baseline: 1.2553x; 1.0137x over previous
//
#include <hip/hip_runtime.h>

#define NSEQ   4096
#define TSTEPS 512
#define FIN    5
#define HID    64
#define SPB    8      // sequences per block — 512 blocks -> 2 blocks/CU (TLP)
#define BLK    512    // 8 waves: w0-3 "G" (gate MFMA + dense epilogue), w4-7 "E" (seed + staging)

// Neutral names — do NOT reuse HIP vector-type names like short8 (R4 crash)
typedef __attribute__((ext_vector_type(8))) short bsh8;    // 8 bf16 in 4 VGPRs
typedef __attribute__((ext_vector_type(4))) float f32x4;   // MFMA accumulator
typedef __attribute__((ext_vector_type(4))) int   i32x4;

#define MFMA16(A, B, C) __builtin_amdgcn_mfma_f32_16x16x32_bf16((A), (B), (C), 0, 0, 0)

// Gate pre-scaling folded into weights/biases so MFMA output is exp2-ready.
//   i,f,o rows scaled by -log2e  -> sigmoid = rcp(1 + exp2(m))
//   g rows scaled by +2*log2e    -> tanh    = (Eg-1)/(Eg+1)
//   c tracked as cs = 2*log2e*c  -> tanh(c) = (Ec-1)/(Ec+1)
#define LOG2E 1.4426950408889634f
#define SNEG  (-LOG2E)
#define SPOS  (2.0f * LOG2E)

struct Frag2 { bsh8 hi; bsh8 lo; };

__device__ __forceinline__ unsigned short bf16hi_rn(float x) {
    unsigned u = __float_as_uint(x);
    return (unsigned short)((u + 0x7fffu + ((u >> 16) & 1u)) >> 16);
}
__device__ __forceinline__ void split_bf16(float v, unsigned short& h, unsigned short& l) {
    h = bf16hi_rn(v);
    float hf_ = __uint_as_float(((unsigned)h) << 16);
    l = bf16hi_rn(v - hf_);
}

__device__ __forceinline__ Frag2 load_whh_frag(const float* __restrict__ Whh, int row, int k, float scale) {
    const float* p = Whh + row * HID + k;
    Frag2 r;
#pragma unroll
    for (int j = 0; j < 8; ++j) {
        unsigned short h, l;
        split_bf16(scale * p[j], h, l);
        r.hi[j] = (short)h; r.lo[j] = (short)l;
    }
    return r;
}
__device__ __forceinline__ Frag2 load_wih_frag(const float* __restrict__ Wih,
                                               const float* __restrict__ bih,
                                               const float* __restrict__ bhh,
                                               int row, int quad, float scale) {
    Frag2 r;
#pragma unroll
    for (int j = 0; j < 8; ++j) { r.hi[j] = 0; r.lo[j] = 0; }
    if (quad == 0) {
        unsigned short h, l;
#pragma unroll
        for (int j = 0; j < FIN; ++j) {
            split_bf16(scale * Wih[row * FIN + j], h, l);
            r.hi[j] = (short)h; r.lo[j] = (short)l;
        }
        split_bf16(scale * (bih[row] + bhh[row]), h, l);
        r.hi[FIN] = (short)h; r.lo[FIN] = (short)l;
    }
    return r;
}

// stage one 32-step x chunk (bf16-hi, 1.0 in bias slot) into dst[32][16]
// (cols 0-7 only; cols 8-15 are permanent zero pad) — E-waves (256 thr, 1 item each)
__device__ __forceinline__ void stage_chunk(const float* __restrict__ feat,
                                            bsh8 (*dst)[16],
                                            int seq0, int t0, int tidE) {
    int t2 = tidE >> 3;
    int s  = tidE & 7;
    const float* xp = feat + (size_t)(seq0 + s) * (TSTEPS * FIN) + (t0 + t2) * FIN;
    bsh8 v = {0, 0, 0, 0, 0, 0, 0, 0};
#pragma unroll
    for (int j = 0; j < FIN; ++j) v[j] = (short)bf16hi_rn(xp[j]);
    v[FIN] = (short)0x3F80;   // bf16(1.0) -> bias k-slot
    dst[t2][s] = v;
}

// Two-element exp2-native LSTM cell epilogue with paired rcp:
//   trans = 5 exp2 + 1 rcp per element (12 wave-instrs for 2 elems).
//   rcp pairing: rcp(D0*D1), then 1/D0 = R*D1. cs is c in 2*log2e scale.
__device__ __forceinline__ void epi2(float zi0, float zf0, float zg0, float zo0,
                                     float zi1, float zf1, float zg1, float zo1,
                                     float& cs0, float& cs1, float& h0, float& h1) {
    float Ei0 = __builtin_amdgcn_exp2f(zi0), Ei1 = __builtin_amdgcn_exp2f(zi1);
    float Ef0 = __builtin_amdgcn_exp2f(zf0), Ef1 = __builtin_amdgcn_exp2f(zf1);
    float Eg0 = __builtin_amdgcn_exp2f(zg0), Eg1 = __builtin_amdgcn_exp2f(zg1);
    float P10 = (1.0f + Ei0) * (1.0f + Eg0), Pf0 = 1.0f + Ef0;
    float P11 = (1.0f + Ei1) * (1.0f + Eg1), Pf1 = 1.0f + Ef1;
    float D0 = P10 * Pf0, D1 = P11 * Pf1;
    float Rp = __builtin_amdgcn_rcpf(D0 * D1);
    float n10 = __builtin_fmaf(SPOS, Eg0, -SPOS);
    float n11 = __builtin_fmaf(SPOS, Eg1, -SPOS);
    float m0 = __builtin_fmaf(P10, cs0, n10 * Pf0);
    float m1 = __builtin_fmaf(P11, cs1, n11 * Pf1);
    cs0 = (Rp * D1) * m0;          // sf*cs + SPOS*sig(i)*tanh(g)
    cs1 = (Rp * D0) * m1;
    float Eo0 = __builtin_amdgcn_exp2f(zo0), Eo1 = __builtin_amdgcn_exp2f(zo1);
    float Ec0 = __builtin_amdgcn_exp2f(cs0), Ec1 = __builtin_amdgcn_exp2f(cs1);
    float D20 = (1.0f + Eo0) * (1.0f + Ec0);
    float D21 = (1.0f + Eo1) * (1.0f + Ec1);
    float R2p = __builtin_amdgcn_rcpf(D20 * D21);
    h0 = (Ec0 - 1.0f) * (R2p * D21);   // sig(o)*tanh(c)
    h1 = (Ec1 - 1.0f) * (R2p * D20);
}

// R7 structure: R6 (SPB=8, 2 independent blocks/CU for cross-block TLP) with
// the register-cap fix. R6's launch_bounds(512,4) behaved as CUDA
// min-BLOCKS-per-CU -> 64-VGPR cap -> ~50 spilled regs -> 24 MB scratch
// traffic on the serial chain. Fix: amdgpu_waves_per_eu(4) (LLVM semantics:
// >=4 waves/EU -> cap = 512/4 = 128) and reduced G pressure:
//   - seed rides the MFMA C-input (E stores raw f32x4; G's 4 ds_read_b128
//     feed the first MFMA of each gate chain) — no post-MFMA seed adds,
//     seed registers die into the MFMAs.
//   - acc densified once via __shfl_xor 32 (quads 2,3 take rows {2,3},{6,7});
//     whole epilogue = ONE epi2 = 12 trans instrs/step.
__global__ __launch_bounds__(BLK) __attribute__((amdgpu_waves_per_eu(4)))
void lstm_kernel(const float* __restrict__ feat,
                 const float* __restrict__ Wih,
                 const float* __restrict__ Whh,
                 const float* __restrict__ bih,
                 const float* __restrict__ bhh,
                 const float* __restrict__ Wd,
                 const float* __restrict__ bd,
                 float* __restrict__ pred,
                 float* __restrict__ accums) {
    __shared__ bsh8  aA[2][16][9];                         // h bf16-hi (rows 8-15 perm. zero)
    __shared__ bsh8  xb[2][32][16];                        // x chunks, cols 8-15 zero pad (16 KB)
    __shared__ __align__(16) f32x4 sg[2][4][4][64];        // raw seed [parity][w][gate][lane] (32 KB)
    __shared__ float hf[SPB][HID + 1];                     // final h fp32
    __shared__ float pf[SPB][17];                          // pred partials

    const int tid   = threadIdx.x;
    const int w     = tid >> 6;
    const int lane  = tid & 63;
    const int col   = lane & 15;       // MFMA col / A-row (seq)
    const int quad  = lane >> 4;
    const int seq0  = blockIdx.x * SPB;

    if (blockIdx.x == 0 && tid < 4) accums[tid] = 0.0f;

    {   // zero aA (both parities; rows 8-15 stay zero forever)
        bsh8 z = {0, 0, 0, 0, 0, 0, 0, 0};
        if (tid < 2 * 16 * 9) (&aA[0][0][0])[tid] = z;
        // zero xb cols 8-15 (both buffers) — staging never touches them
        if (tid < 2 * 32 * 8) {
            int b  = tid >> 8;
            int t2 = (tid >> 3) & 31;
            int s8 = 8 + (tid & 7);
            xb[b][t2][s8] = z;
        }
    }
    if (w >= 4) stage_chunk(feat, xb[0], seq0, 0, tid - 256);

    // lane-dense epilogue row mapping (quads 0..3 -> base rows 0,4,2,6)
    const int rA   = (quad & 1) * 4 + ((quad >> 1) ? 2 : 0);
    const bool loq = (quad < 2);

    if (w < 4) {
        // ---------------- G-waves: h-MFMA (C=seed) + dense epilogue ----------------
        const int u = 16 * w + col;
        const Frag2 b00 = load_whh_frag(Whh, 0*HID + u,      quad*8, SNEG);
        const Frag2 b01 = load_whh_frag(Whh, 0*HID + u, 32 + quad*8, SNEG);
        const Frag2 b10 = load_whh_frag(Whh, 1*HID + u,      quad*8, SNEG);
        const Frag2 b11 = load_whh_frag(Whh, 1*HID + u, 32 + quad*8, SNEG);
        const Frag2 b20 = load_whh_frag(Whh, 2*HID + u,      quad*8, SPOS);
        const Frag2 b21 = load_whh_frag(Whh, 2*HID + u, 32 + quad*8, SPOS);
        const Frag2 b30 = load_whh_frag(Whh, 3*HID + u,      quad*8, SNEG);
        const Frag2 b31 = load_whh_frag(Whh, 3*HID + u, 32 + quad*8, SNEG);

        __syncthreads();   // init + xb[0] staged

        float cs0 = 0.f, cs1 = 0.f;    // c (2*log2e scale) for rows rA, rA+1
        unsigned short* const aAb = (unsigned short*)&aA[0][0][0];
        const int rowbase = rA * 72 + u;       // aA row pitch = 72 shorts
        const int aAhalf  = 16 * 9 * 8;        // shorts per parity buffer
        __builtin_amdgcn_s_setprio(1);         // T5: favor the critical wave

        for (int t = 0; t < TSTEPS; ++t) {
            const int buf = t & 1;
            const int nb  = buf ^ 1;
            __syncthreads();   // h(t-1) + sg[buf] visible

            bsh8 ah0 = aA[buf][col][quad];
            bsh8 ah1 = aA[buf][col][4 + quad];
            f32x4 s0 = sg[buf][w][0][lane];    // C-inputs for the 4 gate chains
            f32x4 s1 = sg[buf][w][1][lane];
            f32x4 s2 = sg[buf][w][2][lane];
            f32x4 s3 = sg[buf][w][3][lane];

            f32x4 acc0 = MFMA16(ah0, b00.hi, s0);
            f32x4 acc1 = MFMA16(ah0, b10.hi, s1);
            f32x4 acc2 = MFMA16(ah0, b20.hi, s2);
            f32x4 acc3 = MFMA16(ah0, b30.hi, s3);
            acc0 = MFMA16(ah1, b01.hi, acc0);
            acc1 = MFMA16(ah1, b11.hi, acc1);
            acc2 = MFMA16(ah1, b21.hi, acc2);
            acc3 = MFMA16(ah1, b31.hi, acc3);
            acc0 = MFMA16(ah0, b00.lo, acc0);
            acc1 = MFMA16(ah0, b10.lo, acc1);
            acc2 = MFMA16(ah0, b20.lo, acc2);
            acc3 = MFMA16(ah0, b30.lo, acc3);
            acc0 = MFMA16(ah1, b01.lo, acc0);
            acc1 = MFMA16(ah1, b11.lo, acc1);
            acc2 = MFMA16(ah1, b21.lo, acc2);
            acc3 = MFMA16(ah1, b31.lo, acc3);

            // dense redistribution: quads 2,3 take rows {2,3},{6,7} from quads 0,1
            float x00 = __shfl_xor(acc0[2], 32, 64), x01 = __shfl_xor(acc0[3], 32, 64);
            float x10 = __shfl_xor(acc1[2], 32, 64), x11 = __shfl_xor(acc1[3], 32, 64);
            float x20 = __shfl_xor(acc2[2], 32, 64), x21 = __shfl_xor(acc2[3], 32, 64);
            float x30 = __shfl_xor(acc3[2], 32, 64), x31 = __shfl_xor(acc3[3], 32, 64);
            float zi0 = loq ? acc0[0] : x00, zi1 = loq ? acc0[1] : x01;
            float zf0 = loq ? acc1[0] : x10, zf1 = loq ? acc1[1] : x11;
            float zg0 = loq ? acc2[0] : x20, zg1 = loq ? acc2[1] : x21;
            float zo0 = loq ? acc3[0] : x30, zo1 = loq ? acc3[1] : x31;

            float h0, h1;
            epi2(zi0, zf0, zg0, zo0, zi1, zf1, zg1, zo1, cs0, cs1, h0, h1);
            unsigned pk;
            asm("v_cvt_pk_bf16_f32 %0, %1, %2" : "=v"(pk) : "v"(h0), "v"(h1));
            unsigned short* hp = aAb + nb * aAhalf + rowbase;
            hp[0]  = (unsigned short)pk;          // row rA
            hp[72] = (unsigned short)(pk >> 16);  // row rA+1
            if (t == TSTEPS - 1) {
                hf[rA + 0][u] = h0;
                hf[rA + 1][u] = h1;
            }
        }
        __builtin_amdgcn_s_setprio(0);
    } else {
        // ---------------- E-waves: x-projection seed + staging ----------------
        const int wE   = w - 4;
        const int tidE = tid - 256;
        const int uE   = 16 * wE + col;
        const Frag2 w0 = load_wih_frag(Wih, bih, bhh, 0*HID + uE, quad, SNEG);
        const Frag2 w1 = load_wih_frag(Wih, bih, bhh, 1*HID + uE, quad, SNEG);
        const Frag2 w2 = load_wih_frag(Wih, bih, bhh, 2*HID + uE, quad, SPOS);
        const Frag2 w3 = load_wih_frag(Wih, bih, bhh, 3*HID + uE, quad, SNEG);

        __syncthreads();   // init + xb[0] staged

        {   // seed(0) -> sg[0] (raw f32x4; before first in-loop barrier)
            bsh8 ax = xb[0][0][col];
            f32x4 e0 = {0.f,0.f,0.f,0.f}, e1 = e0, e2 = e0, e3 = e0;
            e0 = MFMA16(ax, w0.hi, e0); e0 = MFMA16(ax, w0.lo, e0);
            e1 = MFMA16(ax, w1.hi, e1); e1 = MFMA16(ax, w1.lo, e1);
            e2 = MFMA16(ax, w2.hi, e2); e2 = MFMA16(ax, w2.lo, e2);
            e3 = MFMA16(ax, w3.hi, e3); e3 = MFMA16(ax, w3.lo, e3);
            sg[0][wE][0][lane] = e0;
            sg[0][wE][1][lane] = e1;
            sg[0][wE][2][lane] = e2;
            sg[0][wE][3][lane] = e3;
        }
        for (int t = 0; t < TSTEPS; ++t) {
            __syncthreads();   // matches G's per-step barrier
            if ((t & 31) == 0 && t + 32 < TSTEPS)
                stage_chunk(feat, xb[((t >> 5) + 1) & 1], seq0, ((t >> 5) + 1) * 32, tidE);
            if (t + 1 < TSTEPS) {
                const int t1 = t + 1;
                bsh8 ax = xb[(t1 >> 5) & 1][t1 & 31][col];
                f32x4 e0 = {0.f,0.f,0.f,0.f}, e1 = e0, e2 = e0, e3 = e0;
                e0 = MFMA16(ax, w0.hi, e0); e0 = MFMA16(ax, w0.lo, e0);
                e1 = MFMA16(ax, w1.hi, e1); e1 = MFMA16(ax, w1.lo, e1);
                e2 = MFMA16(ax, w2.hi, e2); e2 = MFMA16(ax, w2.lo, e2);
                e3 = MFMA16(ax, w3.hi, e3); e3 = MFMA16(ax, w3.lo, e3);
                const int sb = t1 & 1;
                sg[sb][wE][0][lane] = e0;
                sg[sb][wE][1][lane] = e1;
                sg[sb][wE][2][lane] = e2;
                sg[sb][wE][3][lane] = e3;
            }
        }
    }
    __syncthreads();   // hf visible

    // ---- fused pred head: pred = leaky_relu(h @ Wd^T + bd) ----
    if (tid < 8 * 16) {
        int s  = tid & 7;
        int hq = tid >> 3;           // 16 unit-groups of 4
        int j0 = hq * 4;
        float part = hf[s][j0] * Wd[j0] + hf[s][j0 + 1] * Wd[j0 + 1]
                   + hf[s][j0 + 2] * Wd[j0 + 2] + hf[s][j0 + 3] * Wd[j0 + 3];
        pf[s][hq] = part;
    }
    __syncthreads();
    if (tid < SPB) {
        float sum = bd[0];
#pragma unroll
        for (int j = 0; j < 16; ++j) sum += pf[tid][j];
        float p = (sum >= 0.0f) ? sum : 0.2f * sum;
        pred[seq0 + tid] = p;
    }
}

// fused losses: grid 512 (2 blocks/CU), 8 i-rows per block, f32x4 LDS reads.
// block 0 additionally does the masked-MSE partials.
__global__ __launch_bounds__(256)
void loss_kernel(const float* __restrict__ pred,
                 const float* __restrict__ ret,
                 const int* __restrict__ mask,
                 float* __restrict__ accums) {
    __shared__ __align__(16) float sp[NSEQ];
    __shared__ __align__(16) float sg_[NSEQ];
    __shared__ __align__(16) float sq[NSEQ];
    __shared__ float wsum[8];
    int tid = threadIdx.x;
    for (int idx = tid; idx < NSEQ / 4; idx += 256) {
        f32x4 p4 = ((const f32x4*)pred)[idx];
        f32x4 g4 = ((const f32x4*)ret)[idx];
        i32x4 m4 = ((const i32x4*)mask)[idx];
        f32x4 q4;
#pragma unroll
        for (int l = 0; l < 4; ++l) q4[l] = m4[l] ? 1.0f : 0.0f;
        *(f32x4*)&sp[idx * 4] = p4;
        *(f32x4*)&sg_[idx * 4] = g4;
        *(f32x4*)&sq[idx * 4] = q4;
    }
    __syncthreads();

    if (blockIdx.x == 0) {   // regression loss partials
        float v = 0.0f, m = 0.0f;
        for (int j = tid; j < NSEQ; j += 256) {
            float mj = sq[j];
            float d  = sp[j] - sg_[j];
            v += d * d * mj;
            m += mj;
        }
#pragma unroll
        for (int off = 32; off > 0; off >>= 1) {
            v += __shfl_down(v, off, 64);
            m += __shfl_down(m, off, 64);
        }
        if ((tid & 63) == 0) {
            atomicAdd(&accums[0], v);
            atomicAdd(&accums[1], m);
        }
    }

    int iloc = tid >> 5;          // 8 rows per block
    int jp   = tid & 31;          // 32 lanes per row
    int i    = blockIdx.x * 8 + iloc;
    float pi = sp[i], gi = sg_[i], qi = sq[i];
    float sum = 0.0f;
    for (int j0 = jp * 4; j0 < NSEQ; j0 += 128) {
        f32x4 p4 = *(const f32x4*)&sp[j0];
        f32x4 g4 = *(const f32x4*)&sg_[j0];
        f32x4 q4 = *(const f32x4*)&sq[j0];
#pragma unroll
        for (int l = 0; l < 4; ++l) {
            float t = -(p4[l] - pi) * (g4[l] - gi);
            sum += fmaxf(t, 0.0f) * q4[l];
        }
    }
    sum *= qi;
#pragma unroll
    for (int off = 16; off > 0; off >>= 1) sum += __shfl_down(sum, off, 32);
    if (jp == 0) wsum[iloc] = sum;
    __syncthreads();
    if (tid == 0) {
        float s = wsum[0] + wsum[1] + wsum[2] + wsum[3]
                + wsum[4] + wsum[5] + wsum[6] + wsum[7];
        atomicAdd(&accums[2], s);
    }
}

__global__ void final_kernel(const float* __restrict__ accums,
                             float* __restrict__ out) {
    float reg  = accums[0] / (accums[1] + 1e-8f);
    float rank = accums[2] / 16777216.0f;   // N*N
    out[NSEQ + 0] = reg + rank;
    out[NSEQ + 1] = reg;
    out[NSEQ + 2] = rank;
}

extern "C" void kernel_launch(void* const* d_in, const int* in_sizes, int n_in,
                              void* d_out, int out_size, void* d_ws, size_t ws_size,
                              hipStream_t stream) {
    const float* feat = (const float*)d_in[0];
    const float* ret  = (const float*)d_in[1];
    const int*   mask = (const int*)d_in[2];
    const float* Wih  = (const float*)d_in[3];
    const float* Whh  = (const float*)d_in[4];
    const float* bih  = (const float*)d_in[5];
    const float* bhh  = (const float*)d_in[6];
    const float* Wd   = (const float*)d_in[7];
    const float* bd   = (const float*)d_in[8];
    float* out    = (float*)d_out;
    float* accums = (float*)d_ws;            // [0..3] loss partials

    lstm_kernel<<<NSEQ / SPB, BLK, 0, stream>>>(feat, Wih, Whh, bih, bhh,
                                                Wd, bd, out, accums);
    loss_kernel<<<NSEQ / 8, 256, 0, stream>>>(out, ret, mask, accums);
    final_kernel<<<1, 1, 0, stream>>>(accums, out);
}